// Round 6
// baseline (340.133 us; speedup 1.0000x reference)
//
#include <hip/hip_runtime.h>
#include <hip/hip_bf16.h>
#include <math.h>

typedef short bf16x8 __attribute__((ext_vector_type(8)));
typedef float f32x4 __attribute__((ext_vector_type(4)));
typedef short short4v __attribute__((ext_vector_type(4)));
typedef short short8v __attribute__((ext_vector_type(8)));

__device__ __forceinline__ short f2bf(float f) {
  unsigned u = __builtin_bit_cast(unsigned, f);
  unsigned r = (u + 0x7FFFu + ((u >> 16) & 1u)) >> 16;
  return (short)r;
}
__device__ __forceinline__ float bf2f(short s) {
  unsigned u = ((unsigned)(unsigned short)s) << 16;
  return __builtin_bit_cast(float, u);
}

typedef __attribute__((address_space(1))) const unsigned g_u32;
typedef __attribute__((address_space(3))) unsigned l_u32;
__device__ __forceinline__ void gload_lds16(const short* g, short* l) {
  __builtin_amdgcn_global_load_lds((g_u32*)g, (l_u32*)l, 16, 0, 0);
}

// ---------------- casts ----------------

__global__ __launch_bounds__(256) void k_cast_x(const float* __restrict__ x, short* __restrict__ xb) {
  int tid = blockIdx.x * 256 + threadIdx.x;
  int d4 = tid & 255;
  int sb = tid >> 8;
  int s = sb & 2047;
  int b = sb >> 11;
  float4 v = *((const float4*)(x + (((size_t)s * 8 + b) << 10)) + d4);
  short4v o;
  o.x = f2bf(v.x); o.y = f2bf(v.y); o.z = f2bf(v.z); o.w = f2bf(v.w);
  *((short4v*)(xb + (((size_t)b * 2048 + s) << 10)) + d4) = o;
}

__global__ __launch_bounds__(256) void k_cast_w(const float* __restrict__ Wq, const float* __restrict__ Wk,
                                                const float* __restrict__ Wv, short* __restrict__ Wcat) {
  int tid = blockIdx.x * 256 + threadIdx.x;
  int d4 = tid & 255;
  int n = tid >> 8;
  const float* src = (n < 1024) ? Wq : (n < 2048 ? Wk : Wv);
  int nl = n & 1023;
  float4 v = *((const float4*)(src + ((size_t)nl << 10)) + d4);
  short4v o;
  o.x = f2bf(v.x); o.y = f2bf(v.y); o.z = f2bf(v.z); o.w = f2bf(v.w);
  *((short4v*)(Wcat + ((size_t)n << 10)) + d4) = o;
}

__global__ __launch_bounds__(256) void k_cast_bias(const float* __restrict__ bq, const float* __restrict__ bk,
                                                   const float* __restrict__ bv, float* __restrict__ biascat) {
  int i = blockIdx.x * 256 + threadIdx.x;
  if (i < 3072) biascat[i] = (i < 1024) ? bq[i] : (i < 2048 ? bk[i & 1023] : bv[i & 1023]);
}

// ---------------- 256x256-tile GEMM core: A via LDS, B direct global->reg ----------------
// C[256][256] = A[256, K-contig, LDA] * B^T[256, K-contig, LDB]
// 512 threads = 8 waves (2M x 4N); per-wave 128x64 -> acc[8][4].
// A LDS: [2buf][2 kk-halves of 32][256 rows][32] bf16 = 64 KiB, slot-swizzled
// (slot ^= (row>>1)&3; involution, inverse-swizzled global source) -> 0 conflicts
// (PMC-verified R2-R4). B-fragments load straight from global (L2-resident panels):
// lane pattern row=wn*64+ni*16+(lane&15), k=(lane>>4)*8 -> 16 full 64B lines/instr.
// Per K-tile: ONE barrier + counted vmcnt(4); B double-buffered in 2 static reg sets.
// RACE FIX (R5 NaN): vmcnt(4) assumes stage_A's 4 gload_lds are OLDER than the
// 4 loadB register loads. Source order does not pin VMEM issue order, so a
// sched_barrier(0) is placed immediately after every stage_A issue. This makes
// the end-of-tile vmcnt(4) deterministically drain the LDS stage (and only it),
// keeping the next B-set in flight across the barrier.
template <int LDA, int LDB>
__device__ __forceinline__ void gemm256_core(const short* __restrict__ Ag, const short* __restrict__ Bg,
                                             int NT, short* __restrict__ lds, f32x4 (&acc)[8][4], int tid) {
  const int lane = tid & 63;
  const int wid = tid >> 6;
  const int wm = wid >> 2, wn = wid & 3;
  const int r15 = lane & 15;
  const int g = lane >> 4;
  const int co = ((g ^ ((r15 >> 1) & 3)) << 3);   // swizzled elem offset within 32-elem row
  short* As = lds;

  const short* Brow[4];
#pragma unroll
  for (int ni = 0; ni < 4; ++ni)
    Brow[ni] = Bg + (size_t)(wn * 64 + ni * 16 + r15) * LDB + g * 8;

  auto stage_A = [&](int bufv, int kElem) {   // 4 gload_lds per thread (both kk halves)
#pragma unroll
    for (int kkv = 0; kkv < 2; ++kkv) {
      short* Al = As + (bufv * 2 + kkv) * 8192;
      int ke = kElem + kkv * 32;
#pragma unroll
      for (int i = 0; i < 2; ++i) {
        int c = i * 512 + tid;
        int r = c >> 2, s = c & 3;
        int gk = ke + ((s ^ ((r >> 1) & 3)) << 3);
        gload_lds16(Ag + (size_t)r * LDA + gk, Al + c * 8);
      }
    }
  };

  bf16x8 bS0[4], bS1[4];
  auto loadB = [&](bf16x8 (&dst)[4], int kElem) {
#pragma unroll
    for (int ni = 0; ni < 4; ++ni)
      dst[ni] = *(const bf16x8*)(Brow[ni] + kElem);
  };

  // prologue: A(0) staged (issue pinned oldest), B(0,kk0) in flight
  stage_A(0, 0);
  __builtin_amdgcn_sched_barrier(0);   // pin: stage loads issue before loadB
  loadB(bS0, 0);
  asm volatile("s_waitcnt vmcnt(4)" ::: "memory");   // drain stage only
  __builtin_amdgcn_s_barrier();

  for (int t = 0; t < NT; ++t) {
    const int buf = t & 1;
    const short* A0 = As + ((buf * 2 + 0) * 256 + wm * 128 + r15) * 32 + co;
    const short* A1 = As + ((buf * 2 + 1) * 256 + wm * 128 + r15) * 32 + co;

    {  // kk0
      bf16x8 af[8];
#pragma unroll
      for (int mi = 0; mi < 8; ++mi) af[mi] = *(const bf16x8*)(A0 + mi * 512);
      loadB(bS1, t * 64 + 32);                       // B for kk1, ~1 subphase ahead
      if (t + 1 < NT) {
        stage_A(buf ^ 1, (t + 1) * 64);
        __builtin_amdgcn_sched_barrier(0);           // pin: stage older than next loadB
      }
      __builtin_amdgcn_s_setprio(1);
#pragma unroll
      for (int mi = 0; mi < 8; ++mi)
#pragma unroll
        for (int ni = 0; ni < 4; ++ni)
          acc[mi][ni] = __builtin_amdgcn_mfma_f32_16x16x32_bf16(af[mi], bS0[ni], acc[mi][ni], 0, 0, 0);
      __builtin_amdgcn_s_setprio(0);
    }
    {  // kk1
      bf16x8 ag[8];
#pragma unroll
      for (int mi = 0; mi < 8; ++mi) ag[mi] = *(const bf16x8*)(A1 + mi * 512);
      if (t + 1 < NT) loadB(bS0, (t + 1) * 64);      // B for next tile kk0
      __builtin_amdgcn_s_setprio(1);
#pragma unroll
      for (int mi = 0; mi < 8; ++mi)
#pragma unroll
        for (int ni = 0; ni < 4; ++ni)
          acc[mi][ni] = __builtin_amdgcn_mfma_f32_16x16x32_bf16(ag[mi], bS1[ni], acc[mi][ni], 0, 0, 0);
      __builtin_amdgcn_s_setprio(0);
    }
    if (t + 1 < NT) {
      // stage(t+1) is the oldest outstanding VMEM (pinned): drain it, keep bS0 in flight
      asm volatile("s_waitcnt vmcnt(4)" ::: "memory");
      __builtin_amdgcn_s_barrier();
    }
  }
}

// ---------------- QKV projection: (16384,3072) = Xb (16384,1024) * Wcat^T + bias ----------------
// Q, K stored (B,S,A) bf16; V stored TRANSPOSED as Vt (B,A,S) bf16.
__global__ __launch_bounds__(512, 2) void k_proj(const short* __restrict__ Xb, const short* __restrict__ Wc,
                                                 const float* __restrict__ biascat,
                                                 short* __restrict__ Q, short* __restrict__ K, short* __restrict__ Vt) {
  __shared__ __align__(16) short lds[32768];
  int tid = threadIdx.x;
  int wg = blockIdx.x;                       // 768 blocks
  int swz = (wg & 7) * 96 + (wg >> 3);       // XCD swizzle (768 % 8 == 0, bijective)
  int mt = swz / 12, nt = swz % 12;
  int m0 = mt << 8, n0 = nt << 8;
  f32x4 acc[8][4] = {};
  gemm256_core<1024, 1024>(Xb + (size_t)m0 * 1024, Wc + (size_t)n0 * 1024, 16, lds, acc, tid);
  int lane = tid & 63, wid = tid >> 6;
  int wm = wid >> 2, wn = wid & 3;
  int r15 = lane & 15;
  int which = n0 >> 10;
  int nbase = n0 & 1023;
  if (which == 2) {
#pragma unroll
    for (int ni = 0; ni < 4; ++ni) {
      int cth = wn * 64 + ni * 16 + r15;
      int a = nbase + cth;
      float bv = biascat[n0 + cth];
#pragma unroll
      for (int mi = 0; mi < 8; ++mi) {
        int r = m0 + wm * 128 + mi * 16 + ((lane >> 4) << 2);
        int b = r >> 11, s = r & 2047;
        short4v o;
#pragma unroll
        for (int j = 0; j < 4; ++j) o[j] = f2bf(acc[mi][ni][j] + bv);
        *(short4v*)(Vt + ((size_t)b << 21) + ((size_t)a << 11) + s) = o;
      }
    }
  } else {
    short* outb = (which == 0) ? Q : K;
#pragma unroll
    for (int ni = 0; ni < 4; ++ni) {
      int cth = wn * 64 + ni * 16 + r15;
      float bv = biascat[n0 + cth];
#pragma unroll
      for (int mi = 0; mi < 8; ++mi)
#pragma unroll
        for (int j = 0; j < 4; ++j) {
          int r = m0 + wm * 128 + mi * 16 + ((lane >> 4) << 2) + j;
          outb[((size_t)r << 10) + nbase + cth] = f2bf(acc[mi][ni][j] + bv);
        }
    }
  }
}

// ---------------- QK^T: causal lower-tri 256-tiles, scaled, bf16 scores ----------------
__global__ __launch_bounds__(512, 2) void k_qk(const short* __restrict__ Q, const short* __restrict__ K,
                                               short* __restrict__ Sc) {
  int nt = blockIdx.x, mt = blockIdx.y, b = blockIdx.z;
  if (nt > mt) return;
  __shared__ __align__(16) short lds[32768];
  int tid = threadIdx.x;
  int m0 = mt << 8, n0 = nt << 8;
  const short* Qb = Q + ((size_t)b << 21);
  const short* Kb = K + ((size_t)b << 21);
  f32x4 acc[8][4] = {};
  gemm256_core<1024, 1024>(Qb + (size_t)m0 * 1024, Kb + (size_t)n0 * 1024, 16, lds, acc, tid);
  short* Sb = Sc + ((size_t)b << 22);
  int lane = tid & 63, wid = tid >> 6;
  int wm = wid >> 2, wn = wid & 3;
  int r15 = lane & 15;
#pragma unroll
  for (int mi = 0; mi < 8; ++mi)
#pragma unroll
    for (int ni = 0; ni < 4; ++ni)
#pragma unroll
      for (int j = 0; j < 4; ++j) {
        int r = m0 + wm * 128 + mi * 16 + ((lane >> 4) << 2) + j;
        int c = n0 + wn * 64 + ni * 16 + r15;
        Sb[((size_t)r << 11) + c] = f2bf(acc[mi][ni][j] * 0.03125f);
      }
}

// ---------------- row softmax in-place, causal; zero-fill to 256-tile edge ----------------
__global__ __launch_bounds__(256) void k_softmax(short* __restrict__ Sc) {
  int row = blockIdx.x;
  int b = row >> 11, q = row & 2047;
  short* Pr = Sc + ((size_t)b << 22) + ((size_t)q << 11);
  int T = ((q >> 8) + 1) << 8;          // padded causal length (multiple of 256)
  int tid = threadIdx.x, lane = tid & 63, wid = tid >> 6;
  int k0 = tid << 3;
  float v[8];
  if (k0 < T) {
    short8v raw = *(const short8v*)(Pr + k0);
#pragma unroll
    for (int j = 0; j < 8; ++j) v[j] = (k0 + j <= q) ? bf2f(raw[j]) : -__builtin_inff();
  } else {
#pragma unroll
    for (int j = 0; j < 8; ++j) v[j] = -__builtin_inff();
  }
  float mx = v[0];
#pragma unroll
  for (int j = 1; j < 8; ++j) mx = fmaxf(mx, v[j]);
  for (int off = 1; off < 64; off <<= 1) mx = fmaxf(mx, __shfl_xor(mx, off, 64));
  __shared__ float red[2][4];
  if (lane == 0) red[0][wid] = mx;
  __syncthreads();
  mx = fmaxf(fmaxf(red[0][0], red[0][1]), fmaxf(red[0][2], red[0][3]));
  float e[8], sum = 0.f;
#pragma unroll
  for (int j = 0; j < 8; ++j) {
    e[j] = exp2f((v[j] - mx) * 1.4426950408889634f);
    sum += e[j];
  }
  for (int off = 1; off < 64; off <<= 1) sum += __shfl_xor(sum, off, 64);
  if (lane == 0) red[1][wid] = sum;
  __syncthreads();
  sum = red[1][0] + red[1][1] + red[1][2] + red[1][3];
  float inv = 1.f / sum;
  if (k0 < T) {
    short8v o;
#pragma unroll
    for (int j = 0; j < 8; ++j) o[j] = (k0 + j <= q) ? f2bf(e[j] * inv) : (short)0;
    *(short8v*)(Pr + k0) = o;
  }
}

// ---------------- PV: out (S,B,A) f32 = P (B,S,S) * Vt (B,A,S)^T ----------------
__global__ __launch_bounds__(512, 2) void k_pv(const short* __restrict__ P, const short* __restrict__ Vt,
                                               float* __restrict__ out) {
  int nt = blockIdx.x, mt = blockIdx.y, b = blockIdx.z;
  __shared__ __align__(16) short lds[32768];
  int tid = threadIdx.x;
  int m0 = mt << 8, n0 = nt << 8;
  const short* Pb = P + ((size_t)b << 22);
  const short* Vtb = Vt + ((size_t)b << 21);
  f32x4 acc[8][4] = {};
  gemm256_core<2048, 2048>(Pb + (size_t)m0 * 2048, Vtb + (size_t)n0 * 2048, 4 * (mt + 1), lds, acc, tid);
  int lane = tid & 63, wid = tid >> 6;
  int wm = wid >> 2, wn = wid & 3;
  int r15 = lane & 15;
#pragma unroll
  for (int mi = 0; mi < 8; ++mi)
#pragma unroll
    for (int ni = 0; ni < 4; ++ni)
#pragma unroll
      for (int j = 0; j < 4; ++j) {
        int r = m0 + wm * 128 + mi * 16 + ((lane >> 4) << 2) + j;  // q
        int c = n0 + wn * 64 + ni * 16 + r15;                      // a
        out[((size_t)r << 13) + ((size_t)b << 10) + c] = acc[mi][ni][j];
      }
}

extern "C" void kernel_launch(void* const* d_in, const int* in_sizes, int n_in,
                              void* d_out, int out_size, void* d_ws, size_t ws_size,
                              hipStream_t stream) {
  const float* x  = (const float*)d_in[0];
  const float* Wq = (const float*)d_in[1];
  const float* bq = (const float*)d_in[2];
  const float* Wk = (const float*)d_in[3];
  const float* bk = (const float*)d_in[4];
  const float* Wv = (const float*)d_in[5];
  const float* bv = (const float*)d_in[6];
  float* out = (float*)d_out;
  char* ws = (char*)d_ws;

  short* xb   = (short*)(ws);                    // 33,554,432 B
  short* Wcat = (short*)(ws + 33554432);         //  6,291,456 B
  float* bias = (float*)(ws + 39845888);         //     12,288 B
  short* Q    = (short*)(ws + 39858176);         // 33,554,432 B
  short* K    = (short*)(ws + 73412608);         // 33,554,432 B
  short* Vt   = (short*)(ws + 106967040);        // 33,554,432 B (written transposed by k_proj)
  short* Sc   = (short*)(ws + 140521472);        // 67,108,864 B

  k_cast_x<<<16384, 256, 0, stream>>>(x, xb);
  k_cast_w<<<3072, 256, 0, stream>>>(Wq, Wk, Wv, Wcat);
  k_cast_bias<<<12, 256, 0, stream>>>(bq, bk, bv, bias);
  k_proj<<<768, 512, 0, stream>>>(xb, Wcat, bias, Q, K, Vt);
  k_qk<<<dim3(8, 8, 8), 512, 0, stream>>>(Q, K, Sc);
  k_softmax<<<16384, 256, 0, stream>>>(Sc);
  k_pv<<<dim3(4, 8, 8), 512, 0, stream>>>(Sc, Vt, out);
}

// Round 7
// 298.918 us; speedup vs baseline: 1.1379x; 1.1379x over previous
//
#include <hip/hip_runtime.h>
#include <hip/hip_bf16.h>
#include <math.h>

typedef short bf16x8 __attribute__((ext_vector_type(8)));
typedef float f32x16 __attribute__((ext_vector_type(16)));
typedef short short4v __attribute__((ext_vector_type(4)));
typedef short short8v __attribute__((ext_vector_type(8)));

__device__ __forceinline__ short f2bf(float f) {
  unsigned u = __builtin_bit_cast(unsigned, f);
  unsigned r = (u + 0x7FFFu + ((u >> 16) & 1u)) >> 16;
  return (short)r;
}
__device__ __forceinline__ float bf2f(short s) {
  unsigned u = ((unsigned)(unsigned short)s) << 16;
  return __builtin_bit_cast(float, u);
}

typedef __attribute__((address_space(1))) const unsigned g_u32;
typedef __attribute__((address_space(3))) unsigned l_u32;
__device__ __forceinline__ void gload_lds16(const short* g, short* l) {
  __builtin_amdgcn_global_load_lds((g_u32*)g, (l_u32*)l, 16, 0, 0);
}

// ---------------- casts ----------------

__global__ __launch_bounds__(256) void k_cast_x(const float* __restrict__ x, short* __restrict__ xb) {
  int tid = blockIdx.x * 256 + threadIdx.x;
  int d4 = tid & 255;
  int sb = tid >> 8;
  int s = sb & 2047;
  int b = sb >> 11;
  float4 v = *((const float4*)(x + (((size_t)s * 8 + b) << 10)) + d4);
  short4v o;
  o.x = f2bf(v.x); o.y = f2bf(v.y); o.z = f2bf(v.z); o.w = f2bf(v.w);
  *((short4v*)(xb + (((size_t)b * 2048 + s) << 10)) + d4) = o;
}

__global__ __launch_bounds__(256) void k_cast_w(const float* __restrict__ Wq, const float* __restrict__ Wk,
                                                const float* __restrict__ Wv, short* __restrict__ Wcat) {
  int tid = blockIdx.x * 256 + threadIdx.x;
  int d4 = tid & 255;
  int n = tid >> 8;
  const float* src = (n < 1024) ? Wq : (n < 2048 ? Wk : Wv);
  int nl = n & 1023;
  float4 v = *((const float4*)(src + ((size_t)nl << 10)) + d4);
  short4v o;
  o.x = f2bf(v.x); o.y = f2bf(v.y); o.z = f2bf(v.z); o.w = f2bf(v.w);
  *((short4v*)(Wcat + ((size_t)n << 10)) + d4) = o;
}

__global__ __launch_bounds__(256) void k_cast_bias(const float* __restrict__ bq, const float* __restrict__ bk,
                                                   const float* __restrict__ bv, float* __restrict__ biascat) {
  int i = blockIdx.x * 256 + threadIdx.x;
  if (i < 3072) biascat[i] = (i < 1024) ? bq[i] : (i < 2048 ? bk[i & 1023] : bv[i & 1023]);
}

// ---------------- 256x256-tile GEMM core: 32x32x16 MFMA, balanced 4-phase ----------------
// C[256][256] = A[256, K-contig, LDA] * B^T[256, K-contig, LDB]
// 512 threads = 8 waves (2M x 4N); per-wave 128x64 -> acc[4][2] of f32x16.
// LDS per operand: [2buf][2 K-halves of 32][256 rows][32] bf16; A+B = 128 KiB.
// Slot swizzle (involution, inverse-swizzled global src -> linear LDS dest):
//   slot' = slot ^ ((row>>1)&3). For the 32x32 fragment read pattern
//   (rows = base+(lane&31), chunk = sub*2+(lane>>5)) this spreads each 32-lane
//   half over 16 distinct 16B slots = 2-way = free (0 conflicts R2-R4 family).
// Fragment layouts (32x32x16 bf16): A/B: row|col = lane&31, k = (lane>>5)*8 .. +8.
// C/D: col = lane&31, row = (reg&3) + 8*(reg>>2) + 4*(lane>>5)  [m74/m101].
// Schedule per K-tile t: 4 balanced phases, each {6 ds_read_b128; 2 stage loads;
// barrier; 8 MFMA}. Counted vmcnt(4) at p1/p3 ends (drains exactly the unit-pair
// needed 1 phase later; 3-phase issue-to-drain slack). vmcnt(0) peel on last tile.
template <int LDA, int LDB>
__device__ __forceinline__ void gemm256_core(const short* __restrict__ Ag, const short* __restrict__ Bg,
                                             int NT, short* __restrict__ lds, f32x16 (&acc)[4][2], int tid) {
  const int lane = tid & 63;
  const int wid = tid >> 6;
  const int wm = wid >> 2, wn = wid & 3;
  const int r31 = lane & 31;
  const int hi = lane >> 5;
  const int lswz = (lane >> 1) & 3;          // == ((lane&31)>>1)&3 for all lanes
  short* As = lds;
  short* Bs = lds + 32768;

  auto stage_unit = [&](const short* Gp, int ld, short* Lp, int kbase) {
#pragma unroll
    for (int i = 0; i < 2; ++i) {
      int c = i * 512 + tid;                 // 1024 16B chunks: row=c>>2, slot=c&3
      int r = c >> 2, s = c & 3;
      gload_lds16(Gp + (size_t)r * ld + kbase + ((s ^ ((r >> 1) & 3)) << 3), Lp + c * 8);
    }
  };

  const int aoff = (wm * 128 + r31) * 32;
  const int boff = (wn * 64 + r31) * 32;

  auto rdfrag = [&](int buf, int kk16, bf16x8 (&af)[4], bf16x8 (&bfr)[2]) {
    int h = kk16 >> 1, sub = kk16 & 1;
    int esw = (((sub << 1) | hi) ^ lswz) << 3;
    const short* Ab = As + (buf * 2 + h) * 8192 + aoff + esw;
    const short* Bb = Bs + (buf * 2 + h) * 8192 + boff + esw;
#pragma unroll
    for (int mf = 0; mf < 4; ++mf) af[mf] = *(const bf16x8*)(Ab + mf * 1024);
#pragma unroll
    for (int nf = 0; nf < 2; ++nf) bfr[nf] = *(const bf16x8*)(Bb + nf * 1024);
  };

  auto domfma = [&](bf16x8 (&af)[4], bf16x8 (&bfr)[2]) {
    __builtin_amdgcn_s_setprio(1);
#pragma unroll
    for (int mf = 0; mf < 4; ++mf) {
      acc[mf][0] = __builtin_amdgcn_mfma_f32_32x32x16_bf16(af[mf], bfr[0], acc[mf][0], 0, 0, 0);
      acc[mf][1] = __builtin_amdgcn_mfma_f32_32x32x16_bf16(af[mf], bfr[1], acc[mf][1], 0, 0, 0);
    }
    __builtin_amdgcn_s_setprio(0);
  };

  // prologue: stage tile 0 fully (units: A-h0, B-h0, A-h1, B-h1)
  stage_unit(Ag, LDA, As, 0);
  stage_unit(Bg, LDB, Bs, 0);
  stage_unit(Ag, LDA, As + 8192, 32);
  stage_unit(Bg, LDB, Bs + 8192, 32);
  asm volatile("s_waitcnt vmcnt(4)" ::: "memory");   // drain h0 pair; h1 pair in flight
  __builtin_amdgcn_s_barrier();
  __builtin_amdgcn_sched_barrier(0);

  for (int t = 0; t < NT; ++t) {
    const int buf = t & 1, nb = buf ^ 1;
    const bool more = (t + 1 < NT);
    const int k1 = (t + 1) << 6;
    bf16x8 af[4], bfr[2];

    // p0 (kk16=0, reads h0)
    rdfrag(buf, 0, af, bfr);
    if (more) stage_unit(Ag, LDA, As + nb * 16384, k1);
    __builtin_amdgcn_s_barrier();
    domfma(af, bfr);

    // p1 (kk16=1, reads h0); guard h1 for p2/p3
    rdfrag(buf, 1, af, bfr);
    if (more) {
      stage_unit(Bg, LDB, Bs + nb * 16384, k1);
      asm volatile("s_waitcnt vmcnt(4)" ::: "memory");   // drains this tile's h1 pair
    } else {
      asm volatile("s_waitcnt vmcnt(0)" ::: "memory");
    }
    __builtin_amdgcn_s_barrier();
    __builtin_amdgcn_sched_barrier(0);
    domfma(af, bfr);

    // p2 (kk16=2, reads h1)
    rdfrag(buf, 2, af, bfr);
    if (more) stage_unit(Ag, LDA, As + nb * 16384 + 8192, k1 + 32);
    __builtin_amdgcn_s_barrier();
    domfma(af, bfr);

    // p3 (kk16=3, reads h1); guard next tile's h0
    rdfrag(buf, 3, af, bfr);
    if (more) {
      stage_unit(Bg, LDB, Bs + nb * 16384 + 8192, k1 + 32);
      asm volatile("s_waitcnt vmcnt(4)" ::: "memory");   // drains next tile's h0 pair
      __builtin_amdgcn_s_barrier();
      __builtin_amdgcn_sched_barrier(0);
    }
    domfma(af, bfr);
  }
}

// ---------------- QKV projection: (16384,3072) = Xb (16384,1024) * Wcat^T + bias ----------------
// Q, K stored (B,S,A) bf16; V stored TRANSPOSED as Vt (B,A,S) bf16.
__global__ __launch_bounds__(512, 2) void k_proj(const short* __restrict__ Xb, const short* __restrict__ Wc,
                                                 const float* __restrict__ biascat,
                                                 short* __restrict__ Q, short* __restrict__ K, short* __restrict__ Vt) {
  __shared__ __align__(16) short lds[65536];
  int tid = threadIdx.x;
  int wg = blockIdx.x;                       // 768 blocks
  int swz = (wg & 7) * 96 + (wg >> 3);       // XCD swizzle (768 % 8 == 0, bijective)
  int mt = swz / 12, nt = swz % 12;
  int m0 = mt << 8, n0 = nt << 8;
  f32x16 acc[4][2] = {};
  gemm256_core<1024, 1024>(Xb + (size_t)m0 * 1024, Wc + (size_t)n0 * 1024, 16, lds, acc, tid);
  int lane = tid & 63, wid = tid >> 6;
  int wm = wid >> 2, wn = wid & 3;
  int r31 = lane & 31, hi = lane >> 5;
  int which = n0 >> 10;
  int nbase = n0 & 1023;
  if (which == 2) {
#pragma unroll
    for (int nf = 0; nf < 2; ++nf) {
      int cth = wn * 64 + nf * 32 + r31;
      int a = nbase + cth;
      float bb = biascat[n0 + cth];
#pragma unroll
      for (int mf = 0; mf < 4; ++mf)
#pragma unroll
        for (int q = 0; q < 4; ++q) {
          int rbase = m0 + wm * 128 + mf * 32 + q * 8 + hi * 4;
          int b = rbase >> 11, s = rbase & 2047;
          short4v o;
#pragma unroll
          for (int j = 0; j < 4; ++j) o[j] = f2bf(acc[mf][nf][q * 4 + j] + bb);
          *(short4v*)(Vt + ((size_t)b << 21) + ((size_t)a << 11) + s) = o;
        }
    }
  } else {
    short* outb = (which == 0) ? Q : K;
#pragma unroll
    for (int nf = 0; nf < 2; ++nf) {
      int cth = wn * 64 + nf * 32 + r31;
      float bb = biascat[n0 + cth];
#pragma unroll
      for (int mf = 0; mf < 4; ++mf)
#pragma unroll
        for (int i = 0; i < 16; ++i) {
          int r = m0 + wm * 128 + mf * 32 + (i & 3) + 8 * (i >> 2) + 4 * hi;
          outb[((size_t)r << 10) + nbase + cth] = f2bf(acc[mf][nf][i] + bb);
        }
    }
  }
}

// ---------------- QK^T: causal lower-tri 256-tiles, scaled, bf16 scores ----------------
__global__ __launch_bounds__(512, 2) void k_qk(const short* __restrict__ Q, const short* __restrict__ K,
                                               short* __restrict__ Sc) {
  int nt = blockIdx.x, mt = blockIdx.y, b = blockIdx.z;
  if (nt > mt) return;
  __shared__ __align__(16) short lds[65536];
  int tid = threadIdx.x;
  int m0 = mt << 8, n0 = nt << 8;
  const short* Qb = Q + ((size_t)b << 21);
  const short* Kb = K + ((size_t)b << 21);
  f32x16 acc[4][2] = {};
  gemm256_core<1024, 1024>(Qb + (size_t)m0 * 1024, Kb + (size_t)n0 * 1024, 16, lds, acc, tid);
  short* Sb = Sc + ((size_t)b << 22);
  int lane = tid & 63, wid = tid >> 6;
  int wm = wid >> 2, wn = wid & 3;
  int r31 = lane & 31, hi = lane >> 5;
#pragma unroll
  for (int nf = 0; nf < 2; ++nf) {
    int c = n0 + wn * 64 + nf * 32 + r31;
#pragma unroll
    for (int mf = 0; mf < 4; ++mf)
#pragma unroll
      for (int i = 0; i < 16; ++i) {
        int r = m0 + wm * 128 + mf * 32 + (i & 3) + 8 * (i >> 2) + 4 * hi;
        Sb[((size_t)r << 11) + c] = f2bf(acc[mf][nf][i] * 0.03125f);
      }
  }
}

// ---------------- row softmax in-place, causal; zero-fill to 256-tile edge ----------------
__global__ __launch_bounds__(256) void k_softmax(short* __restrict__ Sc) {
  int row = blockIdx.x;
  int b = row >> 11, q = row & 2047;
  short* Pr = Sc + ((size_t)b << 22) + ((size_t)q << 11);
  int T = ((q >> 8) + 1) << 8;          // padded causal length (multiple of 256)
  int tid = threadIdx.x, lane = tid & 63, wid = tid >> 6;
  int k0 = tid << 3;
  float v[8];
  if (k0 < T) {
    short8v raw = *(const short8v*)(Pr + k0);
#pragma unroll
    for (int j = 0; j < 8; ++j) v[j] = (k0 + j <= q) ? bf2f(raw[j]) : -__builtin_inff();
  } else {
#pragma unroll
    for (int j = 0; j < 8; ++j) v[j] = -__builtin_inff();
  }
  float mx = v[0];
#pragma unroll
  for (int j = 1; j < 8; ++j) mx = fmaxf(mx, v[j]);
  for (int off = 1; off < 64; off <<= 1) mx = fmaxf(mx, __shfl_xor(mx, off, 64));
  __shared__ float red[2][4];
  if (lane == 0) red[0][wid] = mx;
  __syncthreads();
  mx = fmaxf(fmaxf(red[0][0], red[0][1]), fmaxf(red[0][2], red[0][3]));
  float e[8], sum = 0.f;
#pragma unroll
  for (int j = 0; j < 8; ++j) {
    e[j] = exp2f((v[j] - mx) * 1.4426950408889634f);
    sum += e[j];
  }
  for (int off = 1; off < 64; off <<= 1) sum += __shfl_xor(sum, off, 64);
  if (lane == 0) red[1][wid] = sum;
  __syncthreads();
  sum = red[1][0] + red[1][1] + red[1][2] + red[1][3];
  float inv = 1.f / sum;
  if (k0 < T) {
    short8v o;
#pragma unroll
    for (int j = 0; j < 8; ++j) o[j] = (k0 + j <= q) ? f2bf(e[j] * inv) : (short)0;
    *(short8v*)(Pr + k0) = o;
  }
}

// ---------------- PV: out (S,B,A) f32 = P (B,S,S) * Vt (B,A,S)^T ----------------
__global__ __launch_bounds__(512, 2) void k_pv(const short* __restrict__ P, const short* __restrict__ Vt,
                                               float* __restrict__ out) {
  int nt = blockIdx.x, mt = blockIdx.y, b = blockIdx.z;
  __shared__ __align__(16) short lds[65536];
  int tid = threadIdx.x;
  int m0 = mt << 8, n0 = nt << 8;
  const short* Pb = P + ((size_t)b << 22);
  const short* Vtb = Vt + ((size_t)b << 21);
  f32x16 acc[4][2] = {};
  gemm256_core<2048, 2048>(Pb + (size_t)m0 * 2048, Vtb + (size_t)n0 * 2048, 4 * (mt + 1), lds, acc, tid);
  int lane = tid & 63, wid = tid >> 6;
  int wm = wid >> 2, wn = wid & 3;
  int r31 = lane & 31, hi = lane >> 5;
#pragma unroll
  for (int nf = 0; nf < 2; ++nf) {
    int c = n0 + wn * 64 + nf * 32 + r31;
#pragma unroll
    for (int mf = 0; mf < 4; ++mf)
#pragma unroll
      for (int i = 0; i < 16; ++i) {
        int r = m0 + wm * 128 + mf * 32 + (i & 3) + 8 * (i >> 2) + 4 * hi;  // q
        out[((size_t)r << 13) + ((size_t)b << 10) + c] = acc[mf][nf][i];
      }
  }
}

extern "C" void kernel_launch(void* const* d_in, const int* in_sizes, int n_in,
                              void* d_out, int out_size, void* d_ws, size_t ws_size,
                              hipStream_t stream) {
  const float* x  = (const float*)d_in[0];
  const float* Wq = (const float*)d_in[1];
  const float* bq = (const float*)d_in[2];
  const float* Wk = (const float*)d_in[3];
  const float* bk = (const float*)d_in[4];
  const float* Wv = (const float*)d_in[5];
  const float* bv = (const float*)d_in[6];
  float* out = (float*)d_out;
  char* ws = (char*)d_ws;

  short* xb   = (short*)(ws);                    // 33,554,432 B
  short* Wcat = (short*)(ws + 33554432);         //  6,291,456 B
  float* bias = (float*)(ws + 39845888);         //     12,288 B
  short* Q    = (short*)(ws + 39858176);         // 33,554,432 B
  short* K    = (short*)(ws + 73412608);         // 33,554,432 B
  short* Vt   = (short*)(ws + 106967040);        // 33,554,432 B (written transposed by k_proj)
  short* Sc   = (short*)(ws + 140521472);        // 67,108,864 B

  k_cast_x<<<16384, 256, 0, stream>>>(x, xb);
  k_cast_w<<<3072, 256, 0, stream>>>(Wq, Wk, Wv, Wcat);
  k_cast_bias<<<12, 256, 0, stream>>>(bq, bk, bv, bias);
  k_proj<<<768, 512, 0, stream>>>(xb, Wcat, bias, Q, K, Vt);
  k_qk<<<dim3(8, 8, 8), 512, 0, stream>>>(Q, K, Sc);
  k_softmax<<<16384, 256, 0, stream>>>(Sc);
  k_pv<<<dim3(4, 8, 8), 512, 0, stream>>>(Sc, Vt, out);
}

// Round 8
// 284.245 us; speedup vs baseline: 1.1966x; 1.0516x over previous
//
#include <hip/hip_runtime.h>
#include <hip/hip_bf16.h>
#include <math.h>

typedef short bf16x8 __attribute__((ext_vector_type(8)));
typedef float f32x4 __attribute__((ext_vector_type(4)));
typedef short short4v __attribute__((ext_vector_type(4)));
typedef short short8v __attribute__((ext_vector_type(8)));

__device__ __forceinline__ short f2bf(float f) {
  unsigned u = __builtin_bit_cast(unsigned, f);
  unsigned r = (u + 0x7FFFu + ((u >> 16) & 1u)) >> 16;
  return (short)r;
}
__device__ __forceinline__ float bf2f(short s) {
  unsigned u = ((unsigned)(unsigned short)s) << 16;
  return __builtin_bit_cast(float, u);
}

typedef __attribute__((address_space(1))) const unsigned g_u32;
typedef __attribute__((address_space(3))) unsigned l_u32;
__device__ __forceinline__ void gload_lds16(const short* g, short* l) {
  __builtin_amdgcn_global_load_lds((g_u32*)g, (l_u32*)l, 16, 0, 0);
}

#define VMCNT(n) asm volatile("s_waitcnt vmcnt(" #n ")" ::: "memory")

// ---------------- casts ----------------

__global__ __launch_bounds__(256) void k_cast_x(const float* __restrict__ x, short* __restrict__ xb) {
  int tid = blockIdx.x * 256 + threadIdx.x;
  int d4 = tid & 255;
  int sb = tid >> 8;
  int s = sb & 2047;
  int b = sb >> 11;
  float4 v = *((const float4*)(x + (((size_t)s * 8 + b) << 10)) + d4);
  short4v o;
  o.x = f2bf(v.x); o.y = f2bf(v.y); o.z = f2bf(v.z); o.w = f2bf(v.w);
  *((short4v*)(xb + (((size_t)b * 2048 + s) << 10)) + d4) = o;
}

__global__ __launch_bounds__(256) void k_cast_w(const float* __restrict__ Wq, const float* __restrict__ Wk,
                                                const float* __restrict__ Wv, short* __restrict__ Wcat) {
  int tid = blockIdx.x * 256 + threadIdx.x;
  int d4 = tid & 255;
  int n = tid >> 8;
  const float* src = (n < 1024) ? Wq : (n < 2048 ? Wk : Wv);
  int nl = n & 1023;
  float4 v = *((const float4*)(src + ((size_t)nl << 10)) + d4);
  short4v o;
  o.x = f2bf(v.x); o.y = f2bf(v.y); o.z = f2bf(v.z); o.w = f2bf(v.w);
  *((short4v*)(Wcat + ((size_t)n << 10)) + d4) = o;
}

__global__ __launch_bounds__(256) void k_cast_bias(const float* __restrict__ bq, const float* __restrict__ bk,
                                                   const float* __restrict__ bv, float* __restrict__ biascat) {
  int i = blockIdx.x * 256 + threadIdx.x;
  if (i < 3072) biascat[i] = (i < 1024) ? bq[i] : (i < 2048 ? bk[i & 1023] : bv[i & 1023]);
}

// ---------------- 256x256-tile GEMM core: m201-style 4-phase/K-tile, K-chunk ring ----------------
// C[256][256] = A[256, K-contig, LDA] * B^T[256, K-contig, LDB]
// 512 threads = 8 waves (2M x 4N); per-wave 128x64 -> acc[8][4] f32x4 (16x16x32 MFMA).
// LDS: per operand a RING of 4 chunk-slots, each [256 rows][32 k] bf16 = 16KB (A 64K + B 64K).
// K-chunk c (32 k-elems) lives in slot c%4. One MFMA K-step == one chunk.
// Fragment read pattern: rows base+(lane&15), slot g=lane>>4, swizzle slot^=(row>>1)&3 —
// MEASURED 0 bank conflicts (R2/R3). Stage: linear LDS dest, inverse-swizzled global src.
// Per K-tile t (chunks 2t, 2t+1), 4 phases; each phase: {ds_reads; stage 1 chunk-unit;
// [vmcnt]; barrier; lgkmcnt(0); sched_barrier; setprio(1); 16 MFMA; setprio(0); barrier}.
//   p1: rdA(2t,mh0)+rdB(2t), stageA(2t+3)            -> MFMA mh0 x chunk 2t
//   p2: rdA(2t,mh1),         stageB(2t+4), vmcnt(10) -> MFMA mh1 x chunk 2t
//   p3: rdA(2t+1,mh0)+rdB(2t+1), stageA(2t+4)        -> MFMA mh0 x chunk 2t+1
//   p4: rdA(2t+1,mh1),       stageB(2t+5), vmcnt(10) -> MFMA mh1 x chunk 2t+1
// Drain ledger (verified): vmcnt(10) keeps 5 newest units (2 loads each) in flight and
// guarantees the chunks read 1 phase later. Slots are overwritten only 1+ phase after
// their last reader's post-MFMA barrier. Prologue stages B0,A0,B1,A1,B2,A2,B3 oldest-first
// + vmcnt(10); epilogue peels last 2 tiles with vmcnt(8)/(4)/(0).
template <int LDA, int LDB>
__device__ __forceinline__ void gemm256_core(const short* __restrict__ Ag, const short* __restrict__ Bg,
                                             int NT, short* __restrict__ lds, f32x4 (&acc)[8][4], int tid) {
  const int lane = tid & 63;
  const int wid = tid >> 6;
  const int wm = wid >> 2, wn = wid & 3;
  const int r15 = lane & 15;
  const int g = lane >> 4;
  const int co = ((g ^ ((r15 >> 1) & 3)) << 3);
  short* As = lds;             // 4 slots x 8192 shorts
  short* Bs = lds + 32768;

  const int abase = (wm * 128 + r15) * 32 + co;
  const int bbase = (wn * 64 + r15) * 32 + co;

  auto stageA = [&](int c) {
    short* Lp = As + ((c & 3) << 13);
    int kb = c << 5;
#pragma unroll
    for (int i = 0; i < 2; ++i) {
      int ch = i * 512 + tid;
      int r = ch >> 2, s = ch & 3;
      gload_lds16(Ag + (size_t)r * LDA + kb + ((s ^ ((r >> 1) & 3)) << 3), Lp + ch * 8);
    }
  };
  auto stageB = [&](int c) {
    short* Lp = Bs + ((c & 3) << 13);
    int kb = c << 5;
#pragma unroll
    for (int i = 0; i < 2; ++i) {
      int ch = i * 512 + tid;
      int r = ch >> 2, s = ch & 3;
      gload_lds16(Bg + (size_t)r * LDB + kb + ((s ^ ((r >> 1) & 3)) << 3), Lp + ch * 8);
    }
  };

  bf16x8 a4[4], br[4];
  auto rdA = [&](int c, int mh) {
    const short* p = As + ((c & 3) << 13) + abase + (mh << 11);
#pragma unroll
    for (int mf = 0; mf < 4; ++mf) a4[mf] = *(const bf16x8*)(p + mf * 512);
  };
  auto rdB = [&](int c) {
    const short* p = Bs + ((c & 3) << 13) + bbase;
#pragma unroll
    for (int nf = 0; nf < 4; ++nf) br[nf] = *(const bf16x8*)(p + nf * 512);
  };
  auto mm = [&](int mh) {
    __builtin_amdgcn_s_barrier();
    asm volatile("s_waitcnt lgkmcnt(0)" ::: "memory");
    __builtin_amdgcn_sched_barrier(0);
    __builtin_amdgcn_s_setprio(1);
#pragma unroll
    for (int mf = 0; mf < 4; ++mf)
#pragma unroll
      for (int nf = 0; nf < 4; ++nf)
        acc[mh * 4 + mf][nf] =
            __builtin_amdgcn_mfma_f32_16x16x32_bf16(a4[mf], br[nf], acc[mh * 4 + mf][nf], 0, 0, 0);
    __builtin_amdgcn_s_setprio(0);
    __builtin_amdgcn_s_barrier();
  };

  // prologue: 7 chunk-units oldest-first; drain the tile-0 pair
  stageB(0); stageA(0); stageB(1); stageA(1); stageB(2); stageA(2); stageB(3);
  VMCNT(10);
  __builtin_amdgcn_s_barrier();

  for (int t = 0; t + 2 < NT; ++t) {
    const int c0 = 2 * t, c1 = 2 * t + 1;
    rdA(c0, 0); rdB(c0); stageA(c0 + 3);
    mm(0);
    rdA(c0, 1); stageB(c0 + 4); VMCNT(10);
    mm(1);
    rdA(c1, 0); rdB(c1); stageA(c1 + 3);
    mm(0);
    rdA(c1, 1); stageB(c1 + 4); VMCNT(10);
    mm(1);
  }
  {  // t = NT-2: stageB(2NT)/stageA(2NT) don't exist
    const int c0 = 2 * (NT - 2), c1 = c0 + 1;
    rdA(c0, 0); rdB(c0); stageA(c0 + 3);   // = 2NT-1, last unit
    mm(0);
    rdA(c0, 1); VMCNT(8);
    mm(1);
    rdA(c1, 0); rdB(c1);
    mm(0);
    rdA(c1, 1); VMCNT(4);
    mm(1);
  }
  {  // t = NT-1
    const int c0 = 2 * (NT - 1), c1 = c0 + 1;
    rdA(c0, 0); rdB(c0);
    mm(0);
    rdA(c0, 1); VMCNT(0);
    mm(1);
    rdA(c1, 0); rdB(c1);
    mm(0);
    rdA(c1, 1);
    mm(1);
  }
}

// ---------------- QKV projection: (16384,3072) = Xb (16384,1024) * Wcat^T + bias ----------------
// Q, K stored (B,S,A) bf16; V stored TRANSPOSED as Vt (B,A,S) bf16.
__global__ __launch_bounds__(512, 1) void k_proj(const short* __restrict__ Xb, const short* __restrict__ Wc,
                                                 const float* __restrict__ biascat,
                                                 short* __restrict__ Q, short* __restrict__ K, short* __restrict__ Vt) {
  __shared__ __align__(16) short lds[65536];
  int tid = threadIdx.x;
  int wg = blockIdx.x;                       // 768 blocks
  int swz = (wg & 7) * 96 + (wg >> 3);       // XCD swizzle (768 % 8 == 0, bijective)
  int mt = swz / 12, nt = swz % 12;
  int m0 = mt << 8, n0 = nt << 8;
  f32x4 acc[8][4] = {};
  gemm256_core<1024, 1024>(Xb + (size_t)m0 * 1024, Wc + (size_t)n0 * 1024, 16, lds, acc, tid);
  int lane = tid & 63, wid = tid >> 6;
  int wm = wid >> 2, wn = wid & 3;
  int r15 = lane & 15;
  int which = n0 >> 10;
  int nbase = n0 & 1023;
  if (which == 2) {
#pragma unroll
    for (int ni = 0; ni < 4; ++ni) {
      int cth = wn * 64 + ni * 16 + r15;
      int a = nbase + cth;
      float bv = biascat[n0 + cth];
#pragma unroll
      for (int mi = 0; mi < 8; ++mi) {
        int r = m0 + wm * 128 + mi * 16 + ((lane >> 4) << 2);
        int b = r >> 11, s = r & 2047;
        short4v o;
#pragma unroll
        for (int j = 0; j < 4; ++j) o[j] = f2bf(acc[mi][ni][j] + bv);
        *(short4v*)(Vt + ((size_t)b << 21) + ((size_t)a << 11) + s) = o;
      }
    }
  } else {
    short* outb = (which == 0) ? Q : K;
#pragma unroll
    for (int ni = 0; ni < 4; ++ni) {
      int cth = wn * 64 + ni * 16 + r15;
      float bv = biascat[n0 + cth];
#pragma unroll
      for (int mi = 0; mi < 8; ++mi)
#pragma unroll
        for (int j = 0; j < 4; ++j) {
          int r = m0 + wm * 128 + mi * 16 + ((lane >> 4) << 2) + j;
          outb[((size_t)r << 10) + nbase + cth] = f2bf(acc[mi][ni][j] + bv);
        }
    }
  }
}

// ---------------- QK^T: causal lower-tri 256-tiles, scaled, bf16 scores ----------------
__global__ __launch_bounds__(512, 1) void k_qk(const short* __restrict__ Q, const short* __restrict__ K,
                                               short* __restrict__ Sc) {
  int nt = blockIdx.x, mt = blockIdx.y, b = blockIdx.z;
  if (nt > mt) return;
  __shared__ __align__(16) short lds[65536];
  int tid = threadIdx.x;
  int m0 = mt << 8, n0 = nt << 8;
  const short* Qb = Q + ((size_t)b << 21);
  const short* Kb = K + ((size_t)b << 21);
  f32x4 acc[8][4] = {};
  gemm256_core<1024, 1024>(Qb + (size_t)m0 * 1024, Kb + (size_t)n0 * 1024, 16, lds, acc, tid);
  short* Sb = Sc + ((size_t)b << 22);
  int lane = tid & 63, wid = tid >> 6;
  int wm = wid >> 2, wn = wid & 3;
  int r15 = lane & 15;
#pragma unroll
  for (int mi = 0; mi < 8; ++mi)
#pragma unroll
    for (int ni = 0; ni < 4; ++ni)
#pragma unroll
      for (int j = 0; j < 4; ++j) {
        int r = m0 + wm * 128 + mi * 16 + ((lane >> 4) << 2) + j;
        int c = n0 + wn * 64 + ni * 16 + r15;
        Sb[((size_t)r << 11) + c] = f2bf(acc[mi][ni][j] * 0.03125f);
      }
}

// ---------------- row softmax in-place, causal; zero-fill to 256-tile edge ----------------
__global__ __launch_bounds__(256) void k_softmax(short* __restrict__ Sc) {
  int row = blockIdx.x;
  int b = row >> 11, q = row & 2047;
  short* Pr = Sc + ((size_t)b << 22) + ((size_t)q << 11);
  int T = ((q >> 8) + 1) << 8;          // padded causal length (multiple of 256)
  int tid = threadIdx.x, lane = tid & 63, wid = tid >> 6;
  int k0 = tid << 3;
  float v[8];
  if (k0 < T) {
    short8v raw = *(const short8v*)(Pr + k0);
#pragma unroll
    for (int j = 0; j < 8; ++j) v[j] = (k0 + j <= q) ? bf2f(raw[j]) : -__builtin_inff();
  } else {
#pragma unroll
    for (int j = 0; j < 8; ++j) v[j] = -__builtin_inff();
  }
  float mx = v[0];
#pragma unroll
  for (int j = 1; j < 8; ++j) mx = fmaxf(mx, v[j]);
  for (int off = 1; off < 64; off <<= 1) mx = fmaxf(mx, __shfl_xor(mx, off, 64));
  __shared__ float red[2][4];
  if (lane == 0) red[0][wid] = mx;
  __syncthreads();
  mx = fmaxf(fmaxf(red[0][0], red[0][1]), fmaxf(red[0][2], red[0][3]));
  float e[8], sum = 0.f;
#pragma unroll
  for (int j = 0; j < 8; ++j) {
    e[j] = exp2f((v[j] - mx) * 1.4426950408889634f);
    sum += e[j];
  }
  for (int off = 1; off < 64; off <<= 1) sum += __shfl_xor(sum, off, 64);
  if (lane == 0) red[1][wid] = sum;
  __syncthreads();
  sum = red[1][0] + red[1][1] + red[1][2] + red[1][3];
  float inv = 1.f / sum;
  if (k0 < T) {
    short8v o;
#pragma unroll
    for (int j = 0; j < 8; ++j) o[j] = (k0 + j <= q) ? f2bf(e[j] * inv) : (short)0;
    *(short8v*)(Pr + k0) = o;
  }
}

// ---------------- PV: out (S,B,A) f32 = P (B,S,S) * Vt (B,A,S)^T ----------------
__global__ __launch_bounds__(512, 1) void k_pv(const short* __restrict__ P, const short* __restrict__ Vt,
                                               float* __restrict__ out) {
  int nt = blockIdx.x, mt = blockIdx.y, b = blockIdx.z;
  __shared__ __align__(16) short lds[65536];
  int tid = threadIdx.x;
  int m0 = mt << 8, n0 = nt << 8;
  const short* Pb = P + ((size_t)b << 22);
  const short* Vtb = Vt + ((size_t)b << 21);
  f32x4 acc[8][4] = {};
  gemm256_core<2048, 2048>(Pb + (size_t)m0 * 2048, Vtb + (size_t)n0 * 2048, 4 * (mt + 1), lds, acc, tid);
  int lane = tid & 63, wid = tid >> 6;
  int wm = wid >> 2, wn = wid & 3;
  int r15 = lane & 15;
#pragma unroll
  for (int mi = 0; mi < 8; ++mi)
#pragma unroll
    for (int ni = 0; ni < 4; ++ni)
#pragma unroll
      for (int j = 0; j < 4; ++j) {
        int r = m0 + wm * 128 + mi * 16 + ((lane >> 4) << 2) + j;  // q
        int c = n0 + wn * 64 + ni * 16 + r15;                      // a
        out[((size_t)r << 13) + ((size_t)b << 10) + c] = acc[mi][ni][j];
      }
}

extern "C" void kernel_launch(void* const* d_in, const int* in_sizes, int n_in,
                              void* d_out, int out_size, void* d_ws, size_t ws_size,
                              hipStream_t stream) {
  const float* x  = (const float*)d_in[0];
  const float* Wq = (const float*)d_in[1];
  const float* bq = (const float*)d_in[2];
  const float* Wk = (const float*)d_in[3];
  const float* bk = (const float*)d_in[4];
  const float* Wv = (const float*)d_in[5];
  const float* bv = (const float*)d_in[6];
  float* out = (float*)d_out;
  char* ws = (char*)d_ws;

  short* xb   = (short*)(ws);                    // 33,554,432 B
  short* Wcat = (short*)(ws + 33554432);         //  6,291,456 B
  float* bias = (float*)(ws + 39845888);         //     12,288 B
  short* Q    = (short*)(ws + 39858176);         // 33,554,432 B
  short* K    = (short*)(ws + 73412608);         // 33,554,432 B
  short* Vt   = (short*)(ws + 106967040);        // 33,554,432 B (written transposed by k_proj)
  short* Sc   = (short*)(ws + 140521472);        // 67,108,864 B

  k_cast_x<<<16384, 256, 0, stream>>>(x, xb);
  k_cast_w<<<3072, 256, 0, stream>>>(Wq, Wk, Wv, Wcat);
  k_cast_bias<<<12, 256, 0, stream>>>(bq, bk, bv, bias);
  k_proj<<<768, 512, 0, stream>>>(xb, Wcat, bias, Q, K, Vt);
  k_qk<<<dim3(8, 8, 8), 512, 0, stream>>>(Q, K, Sc);
  k_softmax<<<16384, 256, 0, stream>>>(Sc);
  k_pv<<<dim3(4, 8, 8), 512, 0, stream>>>(Sc, Vt, out);
}